// Round 3
// baseline (180.935 us; speedup 1.0000x reference)
//
#include <hip/hip_runtime.h>

// Head: single-head causal attention. B=4, T=2048, D=1024, H=64. fp32 in/out.
// R3: raise wave parallelism + ILP everywhere (R2 was latency-starved at
// 2 waves/SIMD in qkv, 2.25/SIMD in attn).
//  - qkv: split-K x2 (grid 1024, 4096 waves) + unroll-4 k-loop; fp32 partials
//    + reduce kernel (sums halves, bf16-converts, scatters q/k/vT).
//  - attn: split-K flash with 128-key chunks -> 4352 active waves, <=2 tiles
//    each. merge: block per q-tile (2048 waves).
//
// ws layout (bytes):
//   [0,        393216)    Wt   bf16 [192][1024]
//   [393216,  1441792)    q    bf16 [8192][64]
//   [1441792, 2490368)    k    bf16 [8192][64]
//   [2490368, 3538944)    vT   bf16 [4][64][2048]
//   [3538944, 16121856)   pp   fp32 [2][8192][192]   qkv split-K partials
//   [16121856,49676288)   Opart fp32 [8192][16][64]  (id = b*2048+qt*16+kc)
//   [49676288,50200576)   mpart fp32 [8192][16]
//   [50200576,50724864)   lpart fp32 [8192][16]

typedef __attribute__((ext_vector_type(8))) __bf16 bf16x8;
typedef __attribute__((ext_vector_type(4))) float floatx4;

union BF8 {
    bf16x8 v;
    unsigned short s[8];
    uint4 u;
};

__device__ inline unsigned short f2bf(float f) {
    unsigned int u = __float_as_uint(f);
    unsigned int r = (u + 0x7fffu + ((u >> 16) & 1u)) >> 16;
    return (unsigned short)r;
}

// ---------------------------------------------------------------------------
// Kernel 0: Wt[n][kk] = bf16(W_{n/64}[kk][n%64])
// ---------------------------------------------------------------------------
__global__ __launch_bounds__(256) void wt_kernel(const float* __restrict__ Wq,
                                                 const float* __restrict__ Wk,
                                                 const float* __restrict__ Wv,
                                                 unsigned short* __restrict__ wt) {
    int idx = blockIdx.x * 256 + threadIdx.x;
    int kk = idx / 192;
    int n = idx - kk * 192;
    int sel = n >> 6;
    int h = n & 63;
    const float* W = (sel == 0) ? Wq : (sel == 1) ? Wk : Wv;
    wt[(size_t)n * 1024 + kk] = f2bf(W[(size_t)kk * 64 + h]);
}

// ---------------------------------------------------------------------------
// Kernel 1: QKV projection, split-K x2. Grid 1024 x 256. Block = (row-tile 16,
// k-half 512); kh interleaved in blockIdx LSB so both halves of the same rows
// land on adjacent CUs (x L2 reuse). Wave = 16 rows x 48 cols x 512 depth.
// fp32 partials to pp[kh][row][col]. unroll 4 => ~20 loads in flight.
// ---------------------------------------------------------------------------
__global__ __launch_bounds__(256) void qkv_kernel(const float* __restrict__ x,
                                                  const unsigned short* __restrict__ wt,
                                                  float* __restrict__ pp) {
    const int tid = threadIdx.x;
    const int w = tid >> 6;
    const int lane = tid & 63;
    const int quad = lane >> 4;
    const int l16 = lane & 15;
    const int m0 = (blockIdx.x >> 1) * 16;
    const int kh = blockIdx.x & 1;

    floatx4 acc[3];
#pragma unroll
    for (int i = 0; i < 3; ++i) acc[i] = (floatx4)(0.0f);

    const float* xp = x + (size_t)(m0 + l16) * 1024 + kh * 512 + quad * 8;
    const unsigned short* wp = wt + (size_t)(w * 48 + l16) * 1024 + kh * 512 + quad * 8;

#pragma unroll 4
    for (int ks = 0; ks < 16; ++ks) {
        float4 a0 = *(const float4*)(xp + ks * 32);
        float4 a1 = *(const float4*)(xp + ks * 32 + 4);
        BF8 af;
        af.s[0] = f2bf(a0.x); af.s[1] = f2bf(a0.y);
        af.s[2] = f2bf(a0.z); af.s[3] = f2bf(a0.w);
        af.s[4] = f2bf(a1.x); af.s[5] = f2bf(a1.y);
        af.s[6] = f2bf(a1.z); af.s[7] = f2bf(a1.w);
#pragma unroll
        for (int nt = 0; nt < 3; ++nt) {
            BF8 bf_;
            bf_.u = *(const uint4*)(wp + (size_t)nt * 16 * 1024 + ks * 32);
            acc[nt] = __builtin_amdgcn_mfma_f32_16x16x32_bf16(af.v, bf_.v, acc[nt], 0, 0, 0);
        }
    }

    const int row0 = m0 + quad * 4;
    float* base = pp + (size_t)kh * 8192 * 192;
#pragma unroll
    for (int nt = 0; nt < 3; ++nt)
#pragma unroll
        for (int r = 0; r < 4; ++r)
            base[(size_t)(row0 + r) * 192 + w * 48 + nt * 16 + l16] = acc[nt][r];
}

// ---------------------------------------------------------------------------
// Kernel 1b: reduce split-K halves -> bf16 q/k/vT. Grid 6144 x 256,
// one element per thread (n fastest => coalesced pp reads).
// ---------------------------------------------------------------------------
__global__ __launch_bounds__(256) void qkv_reduce(const float* __restrict__ pp,
                                                  unsigned short* __restrict__ qo,
                                                  unsigned short* __restrict__ ko,
                                                  unsigned short* __restrict__ vo) {
    int idx = blockIdx.x * 256 + threadIdx.x;  // 1,572,864
    int m = idx / 192;
    int n = idx - m * 192;
    float v = pp[(size_t)m * 192 + n] + pp[(size_t)(8192 + m) * 192 + n];
    unsigned short val = f2bf(v);
    if (n < 64)
        qo[(size_t)m * 64 + n] = val;
    else if (n < 128)
        ko[(size_t)m * 64 + (n - 64)] = val;
    else
        vo[(size_t)((m >> 11) * 64 + (n - 128)) * 2048 + (m & 2047)] = val;
}

// ---------------------------------------------------------------------------
// Kernel 2: split-K flash pass A, 128-key chunks. Task id in [0,8192):
// b=id>>11, qt=(id>>4)&127, kc=id&15. Active iff kc <= qt>>3 (4352 waves).
// Wave: 16 q-rows, <=2 K-tiles of 64; only diagonal-overlap tiles masked.
// ---------------------------------------------------------------------------
__global__ __launch_bounds__(256) void attn_partial(const unsigned short* __restrict__ qi,
                                                    const unsigned short* __restrict__ ki,
                                                    const unsigned short* __restrict__ vT,
                                                    float* __restrict__ Opart,
                                                    float* __restrict__ mpart,
                                                    float* __restrict__ lpart) {
    __shared__ __align__(16) unsigned short lds_p[4 * 16 * 72];
    const int tid = threadIdx.x;
    const int w = tid >> 6;
    const int lane = tid & 63;
    const int quad = lane >> 4;
    const int l16 = lane & 15;
    const int id = blockIdx.x * 4 + w;
    const int b = id >> 11;
    const int qt = (id >> 4) & 127;
    const int kc = id & 15;
    if (kc > (qt >> 3)) return;
    const int r0 = qt * 16;

    BF8 aq[2];
    {
        const unsigned short* qp = qi + (size_t)(b * 2048 + r0 + l16) * 64 + quad * 8;
        aq[0].u = *(const uint4*)(qp);
        aq[1].u = *(const uint4*)(qp + 32);
    }

    floatx4 oacc[4];
#pragma unroll
    for (int nt = 0; nt < 4; ++nt) oacc[nt] = (floatx4)(0.0f);
    float m_i[4], l_i[4];
#pragma unroll
    for (int r = 0; r < 4; ++r) { m_i[r] = -3.0e38f; l_i[r] = 0.0f; }

    unsigned short* myp = lds_p + w * (16 * 72);

    for (int t = 0; t < 2; ++t) {
        const int j0 = kc * 128 + t * 64;
        if (j0 > r0 + 15) break;

        floatx4 s[4];
#pragma unroll
        for (int nt = 0; nt < 4; ++nt) s[nt] = (floatx4)(0.0f);
#pragma unroll
        for (int kst = 0; kst < 2; ++kst) {
#pragma unroll
            for (int nt = 0; nt < 4; ++nt) {
                BF8 bk;
                bk.u = *(const uint4*)(ki + (size_t)(b * 2048 + j0 + nt * 16 + l16) * 64 +
                                       kst * 32 + quad * 8);
                s[nt] = __builtin_amdgcn_mfma_f32_16x16x32_bf16(aq[kst].v, bk.v, s[nt], 0, 0, 0);
            }
        }

        float sv[4][4];
        const bool masked = (j0 + 63 > r0);
#pragma unroll
        for (int nt = 0; nt < 4; ++nt)
#pragma unroll
            for (int r = 0; r < 4; ++r) {
                float val = s[nt][r] * 0.125f;
                if (masked) {
                    int key = j0 + nt * 16 + l16;
                    int qr = r0 + quad * 4 + r;
                    if (key > qr) val = -3.0e38f;
                }
                sv[nt][r] = val;
            }

        float alpha[4];
#pragma unroll
        for (int r = 0; r < 4; ++r) {
            float mx = fmaxf(fmaxf(sv[0][r], sv[1][r]), fmaxf(sv[2][r], sv[3][r]));
            mx = fmaxf(mx, __shfl_xor(mx, 1));
            mx = fmaxf(mx, __shfl_xor(mx, 2));
            mx = fmaxf(mx, __shfl_xor(mx, 4));
            mx = fmaxf(mx, __shfl_xor(mx, 8));
            float mn = fmaxf(m_i[r], mx);
            alpha[r] = __expf(m_i[r] - mn);
            m_i[r] = mn;
        }
        float rs[4] = {0.f, 0.f, 0.f, 0.f};
#pragma unroll
        for (int nt = 0; nt < 4; ++nt)
#pragma unroll
            for (int r = 0; r < 4; ++r) {
                float p = __expf(sv[nt][r] - m_i[r]);
                sv[nt][r] = p;
                rs[r] += p;
            }
#pragma unroll
        for (int r = 0; r < 4; ++r) {
            float t2 = rs[r];
            t2 += __shfl_xor(t2, 1);
            t2 += __shfl_xor(t2, 2);
            t2 += __shfl_xor(t2, 4);
            t2 += __shfl_xor(t2, 8);
            l_i[r] = l_i[r] * alpha[r] + t2;
        }
#pragma unroll
        for (int nt = 0; nt < 4; ++nt)
#pragma unroll
            for (int r = 0; r < 4; ++r) oacc[nt][r] *= alpha[r];

#pragma unroll
        for (int nt = 0; nt < 4; ++nt)
#pragma unroll
            for (int r = 0; r < 4; ++r)
                myp[(quad * 4 + r) * 72 + nt * 16 + l16] = f2bf(sv[nt][r]);

#pragma unroll
        for (int kst = 0; kst < 2; ++kst) {
            BF8 ap;
            ap.u = *(const uint4*)(myp + l16 * 72 + kst * 32 + quad * 8);
#pragma unroll
            for (int nt = 0; nt < 4; ++nt) {
                BF8 bv;
                bv.u = *(const uint4*)(vT + (size_t)(b * 64 + nt * 16 + l16) * 2048 + j0 +
                                       kst * 32 + quad * 8);
                oacc[nt] = __builtin_amdgcn_mfma_f32_16x16x32_bf16(ap.v, bv.v, oacc[nt], 0, 0, 0);
            }
        }
    }

    const size_t ob = (size_t)id * 1024;
#pragma unroll
    for (int nt = 0; nt < 4; ++nt)
#pragma unroll
        for (int r = 0; r < 4; ++r)
            Opart[ob + (quad * 4 + r) * 64 + nt * 16 + l16] = oacc[nt][r];
    if (l16 == 0) {
#pragma unroll
        for (int r = 0; r < 4; ++r) {
            mpart[id * 16 + quad * 4 + r] = m_i[r];
            lpart[id * 16 + quad * 4 + r] = l_i[r];
        }
    }
}

// ---------------------------------------------------------------------------
// Kernel 3: merge. Block per q-tile (512 blocks x 256). Wave w: rows
// w*4..w*4+3; lane = col. nc = (qt>>3)+1 partials (<=16).
// ---------------------------------------------------------------------------
__global__ __launch_bounds__(256) void attn_merge(const float* __restrict__ Opart,
                                                  const float* __restrict__ mpart,
                                                  const float* __restrict__ lpart,
                                                  float* __restrict__ out) {
    const int tid = threadIdx.x;
    const int w = tid >> 6;
    const int lane = tid & 63;
    const int b = blockIdx.x >> 7;
    const int qt = blockIdx.x & 127;
    const int nc = (qt >> 3) + 1;
    const int base_id = b * 2048 + qt * 16;

#pragma unroll
    for (int rr = 0; rr < 4; ++rr) {
        const int r = w * 4 + rr;
        float M = -3.0e38f;
        for (int c = 0; c < nc; ++c) M = fmaxf(M, mpart[(base_id + c) * 16 + r]);
        float L = 0.0f, O = 0.0f;
        for (int c = 0; c < nc; ++c) {
            float e = __expf(mpart[(base_id + c) * 16 + r] - M);
            L += e * lpart[(base_id + c) * 16 + r];
            O += e * Opart[(size_t)(base_id + c) * 1024 + r * 64 + lane];
        }
        out[(size_t)(b * 2048 + qt * 16 + r) * 64 + lane] = O / L;
    }
}

extern "C" void kernel_launch(void* const* d_in, const int* in_sizes, int n_in,
                              void* d_out, int out_size, void* d_ws, size_t ws_size,
                              hipStream_t stream) {
    const float* x = (const float*)d_in[0];
    const float* Wq = (const float*)d_in[1];
    const float* Wk = (const float*)d_in[2];
    const float* Wv = (const float*)d_in[3];
    float* out = (float*)d_out;

    char* ws = (char*)d_ws;
    unsigned short* wt = (unsigned short*)(ws);
    unsigned short* q = (unsigned short*)(ws + 393216);
    unsigned short* k = (unsigned short*)(ws + 1441792);
    unsigned short* vT = (unsigned short*)(ws + 2490368);
    float* pp = (float*)(ws + 3538944);
    float* Opart = (float*)(ws + 16121856ull);
    float* mpart = (float*)(ws + 49676288ull);
    float* lpart = (float*)(ws + 50200576ull);

    hipLaunchKernelGGL(wt_kernel, dim3(768), dim3(256), 0, stream, Wq, Wk, Wv, wt);
    hipLaunchKernelGGL(qkv_kernel, dim3(1024), dim3(256), 0, stream, x, wt, pp);
    hipLaunchKernelGGL(qkv_reduce, dim3(6144), dim3(256), 0, stream, pp, q, k, vT);
    hipLaunchKernelGGL(attn_partial, dim3(2048), dim3(256), 0, stream, q, k, vT, Opart, mpart, lpart);
    hipLaunchKernelGGL(attn_merge, dim3(512), dim3(256), 0, stream, Opart, mpart, lpart, out);
}